// Round 1
// 3418.923 us; speedup vs baseline: 1.8027x; 1.8027x over previous
//
#include <hip/hip_runtime.h>

// ---------------- problem constants ----------------
static const int N_ROWS = 65536;
static const int E_DIM  = 512;
static const int N_E    = 1024;
static const int NUM_Q  = 4;

// d_out layout (fp32 elements)
static const size_t XQ_OFF   = 0;
static const size_t LOSS_OFF = (size_t)N_ROWS * E_DIM;          // 33554432
static const size_t IDX_OFF  = LOSS_OFF + 1;                    // 33554433
static const size_t DIST_OFF = IDX_OFF + (size_t)N_ROWS * NUM_Q;// 33816577

// ws layout (bytes)
static const size_t WS_RNORM = 0;        // N floats (256 KiB)
static const size_t WS_IDX   = 262144;   // 4*N ints (1 MiB)
static const size_t WS_ENORM = 1310720;  // 1024 floats, reused per stage
static const size_t WS_LPART = 1327104;  // 4*16384 doubles (512 KiB)
static const size_t WS_CBHI  = 1851392;  // 1024*512 halves (1 MiB), per-stage reuse
static const size_t WS_CBLO  = 2899968;  // 1024*512 halves (1 MiB), per-stage reuse
// total ws footprint: 3,948,544 bytes

typedef _Float16 half8 __attribute__((ext_vector_type(8)));
typedef float    f32x4 __attribute__((ext_vector_type(4)));

#define INV2048 4.8828125e-4f   // 2^-11, lo-plane descale

// async global->LDS, 16B per lane. LDS dest = wave-uniform base + lane*16.
__device__ __forceinline__ void gld16(const void* g, void* s) {
    __builtin_amdgcn_global_load_lds(
        (const __attribute__((address_space(1))) unsigned int*)g,
        (__attribute__((address_space(3))) unsigned int*)s, 16, 0, 0);
}

// ---------------- ||x||^2 per row + fp16 hi/lo split of x ----------------
__global__ __launch_bounds__(256) void rnorm_split_kernel(
    const float* __restrict__ x, float* __restrict__ rnorm,
    _Float16* __restrict__ xhi, _Float16* __restrict__ xlo)
{
    const int lane = threadIdx.x & 63;
    const int wave = threadIdx.x >> 6;
    const size_t row = (size_t)blockIdx.x * 4 + wave;
    const float* p = x + row * E_DIM + lane * 8;
    float4 v0 = *(const float4*)p;
    float4 v1 = *(const float4*)(p + 4);
    float vv[8] = {v0.x,v0.y,v0.z,v0.w,v1.x,v1.y,v1.z,v1.w};
    half8 hv, lv;
    float s = 0.f;
#pragma unroll
    for (int e = 0; e < 8; ++e) {
        s += vv[e] * vv[e];
        _Float16 h = (_Float16)vv[e];
        hv[e] = h;
        lv[e] = (_Float16)((vv[e] - (float)h) * 2048.0f);  // exact diff, scaled
    }
    *(half8*)(xhi + row * E_DIM + lane * 8) = hv;
    *(half8*)(xlo + row * E_DIM + lane * 8) = lv;
    for (int off = 32; off; off >>= 1) s += __shfl_down(s, off);
    if (lane == 0) rnorm[row] = s;
}

// ---------------- per-stage codebook: ||e||^2 + fp16 hi/lo split ----------------
__global__ __launch_bounds__(256) void cbsplit_kernel(
    const float* __restrict__ cb,      // codebooks + q*N_E*E_DIM
    float* __restrict__ enorm,         // 1024 floats (stage-local)
    _Float16* __restrict__ bhi, _Float16* __restrict__ blo)
{
    const int lane = threadIdx.x & 63;
    const int wave = threadIdx.x >> 6;
    const int row  = blockIdx.x * 4 + wave;   // 0..1023
    const float* p = cb + (size_t)row * E_DIM + lane * 8;
    float4 v0 = *(const float4*)p;
    float4 v1 = *(const float4*)(p + 4);
    float vv[8] = {v0.x,v0.y,v0.z,v0.w,v1.x,v1.y,v1.z,v1.w};
    half8 hv, lv;
    float s = 0.f;
#pragma unroll
    for (int e = 0; e < 8; ++e) {
        s += vv[e] * vv[e];
        _Float16 h = (_Float16)vv[e];
        hv[e] = h;
        lv[e] = (_Float16)((vv[e] - (float)h) * 2048.0f);
    }
    *(half8*)(bhi + (size_t)row * E_DIM + lane * 8) = hv;
    *(half8*)(blo + (size_t)row * E_DIM + lane * 8) = lv;
    for (int off = 32; off; off >>= 1) s += __shfl_down(s, off);
    if (lane == 0) enorm[row] = s;
}

// ---------------- distance GEMM via fp16x3 split MFMA ----------------
// D = A.B^T emulated as Ahi.Bhi^T + (Ahi.Blo^T + Alo.Bhi^T)*2^-11, fp32 accum.
// 128x128 tile, BK=32, 4 waves (64x64 each), mfma_f32_16x16x32_f16.
__global__ __launch_bounds__(256) void gemm_dist_mfma(
    const _Float16* __restrict__ Ahi, const _Float16* __restrict__ Alo,
    const _Float16* __restrict__ Bhi, const _Float16* __restrict__ Blo,
    const float* __restrict__ rnorm, const float* __restrict__ enorm,
    float* __restrict__ dist)          // dist_out + q*N_E, row stride 4096
{
    __shared__ __align__(16) _Float16 sA[2][128 * 32];   // [hi/lo][row*32+k]
    __shared__ __align__(16) _Float16 sB[2][128 * 32];

    const int tid  = threadIdx.x;
    const int lane = tid & 63;
    const int wave = tid >> 6;

    // XCD-chunked bijective swizzle: 4096 blocks, 512 per XCD.
    // XCD x gets row-panels [x*64, x*64+64), all 8 col-blocks each -> A L2 reuse.
    const int bid = blockIdx.x;
    const int w   = (bid & 7) * 512 + (bid >> 3);
    const int rowBlk = w >> 3;          // 0..511
    const int colBlk = w & 7;           // 0..7
    const size_t rowBase = (size_t)rowBlk * 128;
    const int    colBase = colBlk * 128;

    // staging roles: wave 0->Ahi, 1->Alo, 2->Bhi, 3->Blo (8 KiB plane each)
    const _Float16* gplane;
    _Float16* splane;
    size_t gbase;
    if (wave == 0)      { gplane = Ahi; splane = sA[0]; gbase = rowBase; }
    else if (wave == 1) { gplane = Alo; splane = sA[1]; gbase = rowBase; }
    else if (wave == 2) { gplane = Bhi; splane = sB[0]; gbase = (size_t)colBase; }
    else                { gplane = Blo; splane = sB[1]; gbase = (size_t)colBase; }
    // per-lane source: row = chunk*16 + (lane>>2), k-halves (lane&3)*8
    const _Float16* gp = gplane + (gbase + (size_t)(lane >> 2)) * E_DIM + (lane & 3) * 8;

    // compute geometry: wave (wr,wc) owns 64x64; 4x4 fragments of 16x16
    const int wr  = (wave >> 1) * 64;
    const int wc  = (wave & 1) * 64;
    const int fr  = lane & 15;          // A row / B col within 16
    const int ko  = (lane >> 4) * 8;    // k offset within 32
    const int kg4 = (lane >> 4) * 4;    // C/D row group

    f32x4 acc0[4][4], accx[4][4];
    const f32x4 vzero = {0.f, 0.f, 0.f, 0.f};
#pragma unroll
    for (int m = 0; m < 4; ++m)
#pragma unroll
        for (int n = 0; n < 4; ++n) { acc0[m][n] = vzero; accx[m][n] = vzero; }

    for (int kt = 0; kt < 16; ++kt) {
        // stage tile kt: 8 chunks x 1 KiB per wave (16 rows x 64B each)
#pragma unroll
        for (int c = 0; c < 8; ++c)
            gld16(gp + (size_t)c * 16 * E_DIM + kt * 32, splane + c * 512);
        __syncthreads();   // vmcnt(0) drain -> tile ready

        half8 ah[4], al[4];
#pragma unroll
        for (int m = 0; m < 4; ++m) {
            ah[m] = *(const half8*)&sA[0][(wr + m * 16 + fr) * 32 + ko];
            al[m] = *(const half8*)&sA[1][(wr + m * 16 + fr) * 32 + ko];
        }
#pragma unroll
        for (int n = 0; n < 4; ++n) {
            half8 bh = *(const half8*)&sB[0][(wc + n * 16 + fr) * 32 + ko];
            half8 bl = *(const half8*)&sB[1][(wc + n * 16 + fr) * 32 + ko];
#pragma unroll
            for (int m = 0; m < 4; ++m) {
                acc0[m][n] = __builtin_amdgcn_mfma_f32_16x16x32_f16(ah[m], bh, acc0[m][n], 0, 0, 0);
                accx[m][n] = __builtin_amdgcn_mfma_f32_16x16x32_f16(ah[m], bl, accx[m][n], 0, 0, 0);
                accx[m][n] = __builtin_amdgcn_mfma_f32_16x16x32_f16(al[m], bh, accx[m][n], 0, 0, 0);
            }
        }
        __syncthreads();   // frag reads done before next tile overwrites
    }

    // epilogue: d = (rn - 2*dot) + en; full-line coalesced stores
#pragma unroll
    for (int m = 0; m < 4; ++m) {
        const size_t grow = rowBase + wr + m * 16 + kg4;
        float rn[4];
#pragma unroll
        for (int r = 0; r < 4; ++r) rn[r] = rnorm[grow + r];
#pragma unroll
        for (int n = 0; n < 4; ++n) {
            const int gcol = colBase + wc + n * 16 + fr;
            const float en = enorm[gcol];
#pragma unroll
            for (int r = 0; r < 4; ++r) {
                const float dot = acc0[m][n][r] + accx[m][n][r] * INV2048;
                dist[(grow + r) * (size_t)(NUM_Q * N_E) + gcol] = (rn[r] - 2.0f * dot) + en;
            }
        }
    }
}

// ---------------- argmin per row (np semantics: first min wins) ----------------
__global__ __launch_bounds__(256) void argmin_kernel(const float* __restrict__ dist,
                                                     int* __restrict__ idx_ws,
                                                     float* __restrict__ idx_out) {
    const int lane = threadIdx.x & 63;
    const int wave = threadIdx.x >> 6;
    const size_t row = (size_t)blockIdx.x * 4 + wave;
    const float* dr = dist + row * (NUM_Q * N_E);
    float best = 3.402823466e38f;
    int bi = 0;
#pragma unroll
    for (int t = 0; t < 16; ++t) {
        const int k = lane + t * 64;
        const float v = dr[k];
        if (v < best) { best = v; bi = k; }
    }
    for (int off = 32; off; off >>= 1) {
        const float ov = __shfl_down(best, off);
        const int   oi = __shfl_down(bi, off);
        if (ov < best || (ov == best && oi < bi)) { best = ov; bi = oi; }
    }
    if (lane == 0) {
        idx_ws[row] = bi;
        idx_out[row * NUM_Q] = (float)bi;
    }
}

// ---------------- residual update (in hi/lo planes) + loss partials ----------------
__global__ __launch_bounds__(256) void update_kernel(
    _Float16* __restrict__ rhi, _Float16* __restrict__ rlo,
    const float* __restrict__ cb, const int* __restrict__ idxs,
    float* __restrict__ rnorm_out, double* __restrict__ lpart)
{
    __shared__ double wsum[4];
    const int lane = threadIdx.x & 63;
    const int wave = threadIdx.x >> 6;
    const size_t row = (size_t)blockIdx.x * 4 + wave;
    const int idx = idxs[row];

    half8 h8 = *(const half8*)(rhi + row * E_DIM + lane * 8);
    half8 l8 = *(const half8*)(rlo + row * E_DIM + lane * 8);
    const float* gp = cb + (size_t)idx * E_DIM + lane * 8;
    float4 g0 = *(const float4*)gp, g1 = *(const float4*)(gp + 4);
    float gg[8] = {g0.x,g0.y,g0.z,g0.w,g1.x,g1.y,g1.z,g1.w};

    half8 nh, nl;
    float nrm = 0.f;
    double ls = 0.0;
#pragma unroll
    for (int e = 0; e < 8; ++e) {
        const float rr = (float)h8[e] + (float)l8[e] * INV2048;  // reconstruct residual
        const float t = gg[e] - rr;      // xq - r
        const float s = rr + t;          // straight-through xq_st
        const float rn2 = rr - s;        // new residual (exact ref op order)
        ls  += (double)(t * t);
        nrm += rn2 * rn2;
        _Float16 h = (_Float16)rn2;
        nh[e] = h;
        nl[e] = (_Float16)((rn2 - (float)h) * 2048.0f);
    }
    *(half8*)(rhi + row * E_DIM + lane * 8) = nh;
    *(half8*)(rlo + row * E_DIM + lane * 8) = nl;

    for (int off = 32; off; off >>= 1) {
        nrm += __shfl_down(nrm, off);
        ls  += __shfl_down(ls, off);
    }
    if (lane == 0) {
        rnorm_out[row] = nrm;
        wsum[wave] = ls;
    }
    __syncthreads();
    if (threadIdx.x == 0)
        lpart[blockIdx.x] = ((wsum[0] + wsum[1]) + wsum[2]) + wsum[3];
}

// ---------------- final x_q reconstruction (exact fl-chain replay from x) ----------------
__global__ __launch_bounds__(256) void xq_final_kernel(
    const float* __restrict__ x, const float* __restrict__ codebooks,
    const int* __restrict__ idxs, float* __restrict__ xq_out)
{
    const int lane = threadIdx.x & 63;
    const int wave = threadIdx.x >> 6;
    const size_t row = (size_t)blockIdx.x * 4 + wave;
    const float* xp = x + row * E_DIM + lane * 8;
    float4 r0 = *(const float4*)xp, r1 = *(const float4*)(xp + 4);
    float rr[8] = {r0.x,r0.y,r0.z,r0.w,r1.x,r1.y,r1.z,r1.w};
    float acc[8];

    int id[NUM_Q];
#pragma unroll
    for (int q = 0; q < NUM_Q; ++q) id[q] = idxs[(size_t)q * N_ROWS + row];

#pragma unroll
    for (int q = 0; q < NUM_Q; ++q) {
        const float* gp = codebooks + ((size_t)q * N_E + id[q]) * E_DIM + lane * 8;
        float4 g0 = *(const float4*)gp, g1 = *(const float4*)(gp + 4);
        float gg[8] = {g0.x,g0.y,g0.z,g0.w,g1.x,g1.y,g1.z,g1.w};
#pragma unroll
        for (int e = 0; e < 8; ++e) {
            const float t = gg[e] - rr[e];
            const float s = rr[e] + t;
            rr[e] = rr[e] - s;
            acc[e] = (q == 0) ? s : (acc[e] + s);
        }
    }
    float4 o0 = make_float4(acc[0], acc[1], acc[2], acc[3]);
    float4 o1 = make_float4(acc[4], acc[5], acc[6], acc[7]);
    *(float4*)(xq_out + row * E_DIM + lane * 8)     = o0;
    *(float4*)(xq_out + row * E_DIM + lane * 8 + 4) = o1;
}

// ---------------- loss reduction + final scalar ----------------
__global__ __launch_bounds__(256) void loss_final_kernel(const double* __restrict__ lpart,
                                                         float* __restrict__ out) {
    __shared__ double red[256];
    const int tid = threadIdx.x;
    float l0 = 0.f, l1 = 0.f, l2 = 0.f, l3 = 0.f;
    for (int q = 0; q < NUM_Q; ++q) {
        double s = 0.0;
        for (int i = tid; i < 16384; i += 256) s += lpart[(size_t)q * 16384 + i];
        red[tid] = s;
        __syncthreads();
        for (int st = 128; st; st >>= 1) {
            if (tid < st) red[tid] += red[tid + st];
            __syncthreads();
        }
        if (tid == 0) {
            const float m = (float)(red[0] * (1.0 / 33554432.0));  // /2^25
            const float l = m + 0.25f * m;
            if (q == 0) l0 = l; else if (q == 1) l1 = l; else if (q == 2) l2 = l; else l3 = l;
        }
        __syncthreads();
    }
    if (tid == 0) out[0] = (((l0 + l1) + l2) + l3) * 0.25f;
}

// ---------------- launch ----------------
extern "C" void kernel_launch(void* const* d_in, const int* in_sizes, int n_in,
                              void* d_out, int out_size, void* d_ws, size_t ws_size,
                              hipStream_t stream) {
    const float* x         = (const float*)d_in[0];
    const float* codebooks = (const float*)d_in[1];
    float* out = (float*)d_out;

    float* xq_region = out + XQ_OFF;    // holds residual hi/lo planes during stages
    float* loss_out  = out + LOSS_OFF;
    float* idx_out   = out + IDX_OFF;
    float* dist_out  = out + DIST_OFF;

    _Float16* rhi = (_Float16*)xq_region;                  // 64 MiB plane
    _Float16* rlo = rhi + (size_t)N_ROWS * E_DIM;          // 64 MiB plane

    char* ws = (char*)d_ws;
    float*    rnorm = (float*)(ws + WS_RNORM);
    int*      idxs  = (int*)(ws + WS_IDX);
    float*    enorm = (float*)(ws + WS_ENORM);
    double*   lpart = (double*)(ws + WS_LPART);
    _Float16* cbhi  = (_Float16*)(ws + WS_CBHI);
    _Float16* cblo  = (_Float16*)(ws + WS_CBLO);

    rnorm_split_kernel<<<16384, 256, 0, stream>>>(x, rnorm, rhi, rlo);

    for (int q = 0; q < NUM_Q; ++q) {
        const float* cbq = codebooks + (size_t)q * N_E * E_DIM;
        cbsplit_kernel<<<256, 256, 0, stream>>>(cbq, enorm, cbhi, cblo);
        gemm_dist_mfma<<<4096, 256, 0, stream>>>(
            rhi, rlo, cbhi, cblo, rnorm, enorm, dist_out + (size_t)q * N_E);
        argmin_kernel<<<16384, 256, 0, stream>>>(
            dist_out + (size_t)q * N_E, idxs + (size_t)q * N_ROWS, idx_out + q);
        update_kernel<<<16384, 256, 0, stream>>>(
            rhi, rlo, cbq, idxs + (size_t)q * N_ROWS, rnorm, lpart + (size_t)q * 16384);
    }

    xq_final_kernel<<<16384, 256, 0, stream>>>(x, codebooks, idxs, xq_region);
    loss_final_kernel<<<1, 256, 0, stream>>>(lpart, loss_out);
}